// Round 9
// baseline (437.466 us; speedup 1.0000x reference)
//
#include <hip/hip_runtime.h>
#include <hip/hip_bf16.h>
#include <math.h>

// Problem constants (from reference setup_inputs)
#define BB 32
#define NN 1024
#define DD 64
#define TT 2048
#define CHUNKS (TT / 256)   // 8 column-chunks of 256
#define SEGS 16             // n-segments (decoupled scan)

typedef float f32x4 __attribute__((ext_vector_type(4)));

// alpha is accumulated in LOG2 units: log_prob * log2(e). exp() becomes a
// bare v_exp_f32 (2^x) with no argument scaling.
#define NLOG2E_HALF (-0.72134752044448169f)   // -0.5 * log2(e)

// 2^x via the raw gfx950 instruction (avoid the name __exp2f: it collides
// with a glibc math.h internal declaration -> R8 compile failure).
__device__ __forceinline__ float exp2_fast(float x) {
    return __builtin_amdgcn_exp2f(x);
}

// DPP move WITHOUT tied-old operand -> LLVM fuses it into the consuming
// v_max/v_add as a DPP modifier (1 inst per tree step instead of 3).
template<int CTRL>
__device__ __forceinline__ float dpp_mov_f(float v) {
    return __int_as_float(
        __builtin_amdgcn_mov_dpp(__float_as_int(v), CTRL, 0xF, 0xF, true));
}

// All-lanes butterfly reduce over groups of 2^GB lanes.
template<int GB>
__device__ __forceinline__ float groupMax(float v) {
    v = fmaxf(v, dpp_mov_f<0x0B1>(v));  // quad_perm [1,0,3,2]  -> xor1
    v = fmaxf(v, dpp_mov_f<0x04E>(v));  // quad_perm [2,3,0,1]  -> xor2
    v = fmaxf(v, dpp_mov_f<0x141>(v));  // row_half_mirror      -> xor4
    v = fmaxf(v, dpp_mov_f<0x140>(v));  // row_mirror           -> xor8
    if constexpr (GB == 6) {
        v = fmaxf(v, __shfl_xor(v, 16));
        v = fmaxf(v, __shfl_xor(v, 32));
    }
    return v;
}

template<int GB>
__device__ __forceinline__ float groupSum(float v) {
    v += dpp_mov_f<0x0B1>(v);
    v += dpp_mov_f<0x04E>(v);
    v += dpp_mov_f<0x141>(v);
    v += dpp_mov_f<0x140>(v);
    if constexpr (GB == 6) {
        v += __shfl_xor(v, 16);
        v += __shfl_xor(v, 32);
    }
    return v;
}

__device__ __forceinline__ void loadW(const float* __restrict__ W, int col,
                                      f32x4* wv) {
#pragma unroll
    for (int i = 0; i < 16; ++i) {
        wv[i].x = W[(size_t)(4 * i + 0) * TT + col];
        wv[i].y = W[(size_t)(4 * i + 1) * TT + col];
        wv[i].z = W[(size_t)(4 * i + 2) * TT + col];
        wv[i].w = W[(size_t)(4 * i + 3) * TT + col];
    }
}

__device__ __forceinline__ float hsum(f32x4 s) {
    return (s.x + s.y) + (s.z + s.w);
}

// 4 independent dots vs the same W column; one W read feeds 4 FMAs.
__device__ __forceinline__ void dot4(const float* __restrict__ x0p,
                                     const f32x4* wv,
                                     float& xw0, float& xw1,
                                     float& xw2, float& xw3) {
    const f32x4* xr0 = (const f32x4*)(x0p);
    const f32x4* xr1 = (const f32x4*)(x0p + DD);
    const f32x4* xr2 = (const f32x4*)(x0p + 2 * DD);
    const f32x4* xr3 = (const f32x4*)(x0p + 3 * DD);
    f32x4 s0 = {0.f, 0.f, 0.f, 0.f};
    f32x4 s1 = {0.f, 0.f, 0.f, 0.f};
    f32x4 s2 = {0.f, 0.f, 0.f, 0.f};
    f32x4 s3 = {0.f, 0.f, 0.f, 0.f};
#pragma unroll
    for (int i = 0; i < 16; ++i) {
        const f32x4 w = wv[i];
        s0 += xr0[i] * w;
        s1 += xr1[i] * w;
        s2 += xr2[i] * w;
        s3 += xr3[i] * w;
    }
    xw0 = hsum(s0); xw1 = hsum(s1); xw2 = hsum(s2); xw3 = hsum(s3);
}

// One quad of prefetched inputs: 4 dot products + 4 targets.
struct Quad {
    float xw0, xw1, xw2, xw3;
    float t0, t1, t2, t3;
};

__device__ __forceinline__ Quad load_quad(const float* __restrict__ xb,
                                          const float* __restrict__ tb,
                                          int n, const f32x4* wv) {
    Quad q;
    dot4(xb + (size_t)n * DD, wv, q.xw0, q.xw1, q.xw2, q.xw3);
    q.t0 = tb[n]; q.t1 = tb[n + 1]; q.t2 = tb[n + 2]; q.t3 = tb[n + 3];
    return q;
}

// Pass A: per-(b, t, segment) sum of log-probs (log2 units).
template<int SEG>
__global__ __launch_bounds__(256, 4)
void segsum_kernel(const float* __restrict__ data,
                   const float* __restrict__ targets,
                   const float* __restrict__ W,
                   float* __restrict__ segsum)
{
    constexpr int NSEG = NN / SEG;
    const int blk   = blockIdx.x;
    const int s     = blk % SEG;
    const int rem   = blk / SEG;
    const int chunk = rem % CHUNKS;
    const int b     = rem / CHUNKS;
    const int tid   = threadIdx.x;
    const int col   = chunk * 256 + tid;

    f32x4 wv[16];
    loadW(W, col, wv);

    const float* xb = data + (size_t)b * NN * DD;
    const float* tb = targets + (size_t)b * NN;

    const int n0 = s * NSEG;
    float acc = 0.0f;
    for (int n = n0; n < n0 + NSEG; n += 4) {
        float xw0, xw1, xw2, xw3;
        dot4(xb + (size_t)n * DD, wv, xw0, xw1, xw2, xw3);
        const float t0 = tb[n], t1 = tb[n + 1], t2 = tb[n + 2], t3 = tb[n + 3];
        const float d0 = t0 - xw0;  acc = fmaf(d0 * d0, NLOG2E_HALF, acc);
        const float d1 = t1 - xw1;  acc = fmaf(d1 * d1, NLOG2E_HALF, acc);
        const float d2 = t2 - xw2;  acc = fmaf(d2 * d2, NLOG2E_HALF, acc);
        const float d3 = t3 - xw3;  acc = fmaf(d3 * d3, NLOG2E_HALF, acc);
    }
    segsum[((size_t)b * SEG + s) * TT + col] = acc;
}

// Pass B: software-pipelined local scan. The next quad's dot4 (x loads +
// 256 independent FMAs) is issued BEFORE the current quad's softmax, so
// load latency and the serial DPP/exp chains overlap with FMA issue.
template<int SEG, int GB>
__global__ __launch_bounds__(256, 4)
void scan_kernel(const float* __restrict__ data,
                 const float* __restrict__ targets,
                 const float* __restrict__ W,
                 const float* __restrict__ segsum,
                 float* __restrict__ mP,
                 float* __restrict__ sP,
                 float* __restrict__ pP)
{
    constexpr int NSEG  = NN / SEG;
    constexpr int QUADS = NSEG / 4;
    constexpr int PPN   = TT >> GB;           // partials per (b,n)
    const int blk   = blockIdx.x;
    const int s     = blk % SEG;
    const int rem   = blk / SEG;
    const int chunk = rem % CHUNKS;
    const int b     = rem / CHUNKS;
    const int tid   = threadIdx.x;
    const int lane  = tid & 63;
    const int col   = chunk * 256 + tid;

    f32x4 wv[16];
    loadW(W, col, wv);

    const float* xb = data + (size_t)b * NN * DD;
    const float* tb = targets + (size_t)b * NN;

    const int  k      = (chunk * 256 + (tid & ~((1 << GB) - 1))) >> GB;
    const bool writer = (lane & ((1 << GB) - 1)) == 0;
    const size_t base0 = (size_t)b * NN * PPN + k;

    // exclusive segment prefix (log2 units)
    float alpha = 0.0f;
    if constexpr (SEG > 1) {
        for (int s2 = 0; s2 < s; ++s2)
            alpha += segsum[((size_t)b * SEG + s2) * TT + col];
    }

    const int n0 = s * NSEG;

    // softmax + emit for one quad; updates alpha.
    auto emit = [&](const Quad& qd, int n) {
        // Phase 1: exclusive alphas (short serial chain).
        const float a0 = alpha;
        const float d0 = qd.t0 - qd.xw0;  const float a1 = fmaf(d0 * d0, NLOG2E_HALF, a0);
        const float d1 = qd.t1 - qd.xw1;  const float a2 = fmaf(d1 * d1, NLOG2E_HALF, a1);
        const float d2 = qd.t2 - qd.xw2;  const float a3 = fmaf(d2 * d2, NLOG2E_HALF, a2);
        const float d3 = qd.t3 - qd.xw3;  alpha           = fmaf(d3 * d3, NLOG2E_HALF, a3);

        // Phase 2: per-point max trees (required: inter-point drops are
        // huge, any stale shift underflows all lanes -> 0/0 in combine).
        const float m0 = groupMax<GB>(a0);
        const float m1 = groupMax<GB>(a1);
        const float m2 = groupMax<GB>(a2);
        const float m3 = groupMax<GB>(a3);

        // Phase 3: bare v_exp_f32 (alpha already in log2 units).
        const float e0 = exp2_fast(a0 - m0);
        const float e1 = exp2_fast(a1 - m1);
        const float e2 = exp2_fast(a2 - m2);
        const float e3 = exp2_fast(a3 - m3);
        const float q0 = e0 * qd.xw0, q1 = e1 * qd.xw1;
        const float q2 = e2 * qd.xw2, q3 = e3 * qd.xw3;

        // Phase 4: 8 independent sum trees.
        const float sv0 = groupSum<GB>(e0);
        const float sv1 = groupSum<GB>(e1);
        const float sv2 = groupSum<GB>(e2);
        const float sv3 = groupSum<GB>(e3);
        const float pv0 = groupSum<GB>(q0);
        const float pv1 = groupSum<GB>(q1);
        const float pv2 = groupSum<GB>(q2);
        const float pv3 = groupSum<GB>(q3);

        // Phase 5: batched writer stores (imm-offset folded).
        if (writer) {
            const size_t i0 = base0 + (size_t)n * PPN;
            const size_t i1 = i0 + PPN;
            const size_t i2 = i0 + 2 * PPN;
            const size_t i3 = i0 + 3 * PPN;
            mP[i0] = m0;  sP[i0] = sv0;  pP[i0] = pv0;
            mP[i1] = m1;  sP[i1] = sv1;  pP[i1] = pv1;
            mP[i2] = m2;  sP[i2] = sv2;  pP[i2] = pv2;
            mP[i3] = m3;  sP[i3] = sv3;  pP[i3] = pv3;
        }
    };

    Quad cur = load_quad(xb, tb, n0, wv);
#pragma unroll 1
    for (int q = 0; q < QUADS - 1; ++q) {
        Quad nxt = load_quad(xb, tb, n0 + 4 * q + 4, wv);  // prefetch
        emit(cur, n0 + 4 * q);                              // overlaps with nxt's FMAs
        cur = nxt;
    }
    emit(cur, n0 + NSEG - 4);
}

// Pass C: one wave per (b,n): merge PPN partials (log2 units).
template<int PPN>
__global__ __launch_bounds__(256)
void combine_kernel(const float* __restrict__ mP,
                    const float* __restrict__ sP,
                    const float* __restrict__ pP,
                    float* __restrict__ out)
{
    const int wgid = blockIdx.x * 4 + (threadIdx.x >> 6);   // = b*NN + n
    const int lane = threadIdx.x & 63;
    const size_t base = (size_t)wgid * PPN;

    float m = -INFINITY, s = 0.0f, p = 0.0f;
    if constexpr (PPN >= 64) {
#pragma unroll
        for (int j = 0; j < PPN / 64; ++j) {
            const size_t idx = base + lane + j * 64;
            const float mk = mP[idx], sk = sP[idx], pk = pP[idx];
            const float M  = fmaxf(m, mk);
            const float e1 = exp2_fast(m - M), e2 = exp2_fast(mk - M);
            s = s * e1 + sk * e2;
            p = p * e1 + pk * e2;
            m = M;
        }
    } else {
        if (lane < PPN) {
            m = mP[base + lane]; s = sP[base + lane]; p = pP[base + lane];
        }
    }

#pragma unroll
    for (int off = 1; off < 64; off <<= 1) {
        const float mo = __shfl_xor(m, off);
        const float so = __shfl_xor(s, off);
        const float po = __shfl_xor(p, off);
        const float M  = fmaxf(m, mo);
        const float e1 = exp2_fast(m - M), e2 = exp2_fast(mo - M);
        s = s * e1 + so * e2;
        p = p * e1 + po * e2;
        m = M;
    }

    if (lane == 0) out[wgid] = p / s;
}

extern "C" void kernel_launch(void* const* d_in, const int* in_sizes, int n_in,
                              void* d_out, int out_size, void* d_ws, size_t ws_size,
                              hipStream_t stream)
{
    (void)in_sizes; (void)n_in; (void)out_size;
    const float* data    = (const float*)d_in[0];
    const float* targets = (const float*)d_in[1];
    const float* W       = (const float*)d_in[2];
    float* out = (float*)d_out;

    const size_t plane4 = (size_t)BB * NN * (TT >> 4);   // GB=4: 128 partials/(b,n)
    const size_t plane6 = (size_t)BB * NN * (TT >> 6);   // GB=6: 32 partials/(b,n)
    const size_t segN   = (size_t)BB * SEGS * TT;

    if (ws_size >= (3 * plane4 + segN) * sizeof(float)) {
        // ~52 MB path: SEG=16, GB=4 (DPP-only reductions)
        float* mP = (float*)d_ws;
        float* sP = mP + plane4;
        float* pP = sP + plane4;
        float* sg = pP + plane4;
        segsum_kernel<SEGS><<<BB * CHUNKS * SEGS, 256, 0, stream>>>(data, targets, W, sg);
        scan_kernel<SEGS, 4><<<BB * CHUNKS * SEGS, 256, 0, stream>>>(data, targets, W, sg, mP, sP, pP);
        combine_kernel<128><<<(BB * NN) / 4, 256, 0, stream>>>(mP, sP, pP, out);
    } else if (ws_size >= (3 * plane6 + segN) * sizeof(float)) {
        // ~17 MB path: SEG=16, GB=6
        float* mP = (float*)d_ws;
        float* sP = mP + plane6;
        float* pP = sP + plane6;
        float* sg = pP + plane6;
        segsum_kernel<SEGS><<<BB * CHUNKS * SEGS, 256, 0, stream>>>(data, targets, W, sg);
        scan_kernel<SEGS, 6><<<BB * CHUNKS * SEGS, 256, 0, stream>>>(data, targets, W, sg, mP, sP, pP);
        combine_kernel<32><<<(BB * NN) / 4, 256, 0, stream>>>(mP, sP, pP, out);
    } else {
        // 12 MB fallback: no segmentation (slow but correct)
        float* mP = (float*)d_ws;
        float* sP = mP + plane6;
        float* pP = sP + plane6;
        scan_kernel<1, 6><<<BB * CHUNKS, 256, 0, stream>>>(data, targets, W, nullptr, mP, sP, pP);
        combine_kernel<32><<<(BB * NN) / 4, 256, 0, stream>>>(mP, sP, pP, out);
    }
}

// Round 10
// 340.012 us; speedup vs baseline: 1.2866x; 1.2866x over previous
//
#include <hip/hip_runtime.h>
#include <hip/hip_bf16.h>
#include <math.h>

// Problem constants (from reference setup_inputs)
#define BB 32
#define NN 1024
#define DD 64
#define TT 2048
#define CHUNKS (TT / 256)   // 8 column-chunks of 256

typedef float f32x4 __attribute__((ext_vector_type(4)));

// alpha is accumulated in LOG2 units: log_prob * log2(e). exp() becomes a
// bare v_exp_f32 (2^x). Validated in R9: absmax 0.0625.
#define NLOG2E_HALF (-0.72134752044448169f)   // -0.5 * log2(e)

// 2^x via the raw instruction (name __exp2f collides with glibc math.h).
__device__ __forceinline__ float exp2_fast(float x) {
    return __builtin_amdgcn_exp2f(x);
}

// DPP move WITHOUT tied-old operand -> fuses into the consumer op.
template<int CTRL>
__device__ __forceinline__ float dpp_mov_f(float v) {
    return __int_as_float(
        __builtin_amdgcn_mov_dpp(__float_as_int(v), CTRL, 0xF, 0xF, true));
}

// All-lanes butterfly reduce over groups of 2^GB lanes.
template<int GB>
__device__ __forceinline__ float groupMax(float v) {
    v = fmaxf(v, dpp_mov_f<0x0B1>(v));  // quad_perm [1,0,3,2]  -> xor1
    v = fmaxf(v, dpp_mov_f<0x04E>(v));  // quad_perm [2,3,0,1]  -> xor2
    v = fmaxf(v, dpp_mov_f<0x141>(v));  // row_half_mirror      -> xor4
    v = fmaxf(v, dpp_mov_f<0x140>(v));  // row_mirror           -> xor8
    if constexpr (GB == 6) {
        v = fmaxf(v, __shfl_xor(v, 16));
        v = fmaxf(v, __shfl_xor(v, 32));
    }
    return v;
}

template<int GB>
__device__ __forceinline__ float groupSum(float v) {
    v += dpp_mov_f<0x0B1>(v);
    v += dpp_mov_f<0x04E>(v);
    v += dpp_mov_f<0x141>(v);
    v += dpp_mov_f<0x140>(v);
    if constexpr (GB == 6) {
        v += __shfl_xor(v, 16);
        v += __shfl_xor(v, 32);
    }
    return v;
}

__device__ __forceinline__ void loadW(const float* __restrict__ W, int col,
                                      f32x4* wv) {
#pragma unroll
    for (int i = 0; i < 16; ++i) {
        wv[i].x = W[(size_t)(4 * i + 0) * TT + col];
        wv[i].y = W[(size_t)(4 * i + 1) * TT + col];
        wv[i].z = W[(size_t)(4 * i + 2) * TT + col];
        wv[i].w = W[(size_t)(4 * i + 3) * TT + col];
    }
}

__device__ __forceinline__ float hsum(f32x4 s) {
    return (s.x + s.y) + (s.z + s.w);
}

// 4 independent dots vs the same W column; one W read feeds 4 FMAs.
// Plain loop + default unrolling: the compiler schedules this better than
// any manual pipeline (R9 lesson: manual Quad/unroll-1 was 2.2x VALU ops).
__device__ __forceinline__ void dot4(const float* __restrict__ x0p,
                                     const f32x4* wv,
                                     float& xw0, float& xw1,
                                     float& xw2, float& xw3) {
    const f32x4* xr0 = (const f32x4*)(x0p);
    const f32x4* xr1 = (const f32x4*)(x0p + DD);
    const f32x4* xr2 = (const f32x4*)(x0p + 2 * DD);
    const f32x4* xr3 = (const f32x4*)(x0p + 3 * DD);
    f32x4 s0 = {0.f, 0.f, 0.f, 0.f};
    f32x4 s1 = {0.f, 0.f, 0.f, 0.f};
    f32x4 s2 = {0.f, 0.f, 0.f, 0.f};
    f32x4 s3 = {0.f, 0.f, 0.f, 0.f};
#pragma unroll
    for (int i = 0; i < 16; ++i) {
        const f32x4 w = wv[i];
        s0 += xr0[i] * w;
        s1 += xr1[i] * w;
        s2 += xr2[i] * w;
        s3 += xr3[i] * w;
    }
    xw0 = hsum(s0); xw1 = hsum(s1); xw2 = hsum(s2); xw3 = hsum(s3);
}

// Pass A: per-(b, t, segment) sum of log-probs (log2 units).
template<int SEG>
__global__ __launch_bounds__(256, 4)
void segsum_kernel(const float* __restrict__ data,
                   const float* __restrict__ targets,
                   const float* __restrict__ W,
                   float* __restrict__ segsum)
{
    constexpr int NSEG = NN / SEG;
    const int blk   = blockIdx.x;
    const int s     = blk % SEG;
    const int rem   = blk / SEG;
    const int chunk = rem % CHUNKS;
    const int b     = rem / CHUNKS;
    const int tid   = threadIdx.x;
    const int col   = chunk * 256 + tid;

    f32x4 wv[16];
    loadW(W, col, wv);

    const float* xb = data + (size_t)b * NN * DD;
    const float* tb = targets + (size_t)b * NN;

    const int n0 = s * NSEG;
    float acc = 0.0f;
    for (int n = n0; n < n0 + NSEG; n += 4) {
        float xw0, xw1, xw2, xw3;
        dot4(xb + (size_t)n * DD, wv, xw0, xw1, xw2, xw3);
        const float t0 = tb[n], t1 = tb[n + 1], t2 = tb[n + 2], t3 = tb[n + 3];
        const float d0 = t0 - xw0;  acc = fmaf(d0 * d0, NLOG2E_HALF, acc);
        const float d1 = t1 - xw1;  acc = fmaf(d1 * d1, NLOG2E_HALF, acc);
        const float d2 = t2 - xw2;  acc = fmaf(d2 * d2, NLOG2E_HALF, acc);
        const float d3 = t3 - xw3;  acc = fmaf(d3 * d3, NLOG2E_HALF, acc);
    }
    segsum[((size_t)b * SEG + s) * TT + col] = acc;
}

// Pass B: local scan seeded with segment prefix (R7 structure: plain loop,
// compiler-scheduled). Emits per-2^GB-lane-group softmax partials (m, s, p).
template<int SEG, int GB>
__global__ __launch_bounds__(256, 4)
void scan_kernel(const float* __restrict__ data,
                 const float* __restrict__ targets,
                 const float* __restrict__ W,
                 const float* __restrict__ segsum,
                 float* __restrict__ mP,
                 float* __restrict__ sP,
                 float* __restrict__ pP)
{
    constexpr int NSEG = NN / SEG;
    constexpr int PPN  = TT >> GB;            // partials per (b,n)
    const int blk   = blockIdx.x;
    const int s     = blk % SEG;
    const int rem   = blk / SEG;
    const int chunk = rem % CHUNKS;
    const int b     = rem / CHUNKS;
    const int tid   = threadIdx.x;
    const int lane  = tid & 63;
    const int col   = chunk * 256 + tid;

    f32x4 wv[16];
    loadW(W, col, wv);

    const float* xb = data + (size_t)b * NN * DD;
    const float* tb = targets + (size_t)b * NN;

    const int  k      = (chunk * 256 + (tid & ~((1 << GB) - 1))) >> GB;
    const bool writer = (lane & ((1 << GB) - 1)) == 0;
    const size_t base0 = (size_t)b * NN * PPN + k;

    // exclusive segment prefix (log2 units)
    float alpha = 0.0f;
    if constexpr (SEG > 1) {
        for (int s2 = 0; s2 < s; ++s2)
            alpha += segsum[((size_t)b * SEG + s2) * TT + col];
    }

    const int n0 = s * NSEG;
    for (int n = n0; n < n0 + NSEG; n += 4) {
        float xw0, xw1, xw2, xw3;
        dot4(xb + (size_t)n * DD, wv, xw0, xw1, xw2, xw3);

        // Phase 1: exclusive alphas (short serial chain).
        const float a0 = alpha;
        const float d0 = tb[n + 0] - xw0;  const float a1 = fmaf(d0 * d0, NLOG2E_HALF, a0);
        const float d1 = tb[n + 1] - xw1;  const float a2 = fmaf(d1 * d1, NLOG2E_HALF, a1);
        const float d2 = tb[n + 2] - xw2;  const float a3 = fmaf(d2 * d2, NLOG2E_HALF, a2);
        const float d3 = tb[n + 3] - xw3;  alpha           = fmaf(d3 * d3, NLOG2E_HALF, a3);

        // Phase 2: per-point max trees (required; stale shifts underflow —
        // mean alpha drop is ~47 log2-units per point).
        const float m0 = groupMax<GB>(a0);
        const float m1 = groupMax<GB>(a1);
        const float m2 = groupMax<GB>(a2);
        const float m3 = groupMax<GB>(a3);

        // Phase 3: bare v_exp_f32 (alpha in log2 units).
        const float e0 = exp2_fast(a0 - m0);
        const float e1 = exp2_fast(a1 - m1);
        const float e2 = exp2_fast(a2 - m2);
        const float e3 = exp2_fast(a3 - m3);
        const float q0 = e0 * xw0, q1 = e1 * xw1;
        const float q2 = e2 * xw2, q3 = e3 * xw3;

        // Phase 4: 8 independent sum trees.
        const float sv0 = groupSum<GB>(e0);
        const float sv1 = groupSum<GB>(e1);
        const float sv2 = groupSum<GB>(e2);
        const float sv3 = groupSum<GB>(e3);
        const float pv0 = groupSum<GB>(q0);
        const float pv1 = groupSum<GB>(q1);
        const float pv2 = groupSum<GB>(q2);
        const float pv3 = groupSum<GB>(q3);

        // Phase 5: batched writer stores (imm-offset folded).
        if (writer) {
            const size_t i0 = base0 + (size_t)n * PPN;
            const size_t i1 = i0 + PPN;
            const size_t i2 = i0 + 2 * PPN;
            const size_t i3 = i0 + 3 * PPN;
            mP[i0] = m0;  sP[i0] = sv0;  pP[i0] = pv0;
            mP[i1] = m1;  sP[i1] = sv1;  pP[i1] = pv1;
            mP[i2] = m2;  sP[i2] = sv2;  pP[i2] = pv2;
            mP[i3] = m3;  sP[i3] = sv3;  pP[i3] = pv3;
        }
    }
}

// Pass C: one wave per (b,n): merge PPN partials (log2 units).
template<int PPN>
__global__ __launch_bounds__(256)
void combine_kernel(const float* __restrict__ mP,
                    const float* __restrict__ sP,
                    const float* __restrict__ pP,
                    float* __restrict__ out)
{
    const int wgid = blockIdx.x * 4 + (threadIdx.x >> 6);   // = b*NN + n
    const int lane = threadIdx.x & 63;
    const size_t base = (size_t)wgid * PPN;

    float m = -INFINITY, s = 0.0f, p = 0.0f;
    if constexpr (PPN >= 64) {
#pragma unroll
        for (int j = 0; j < PPN / 64; ++j) {
            const size_t idx = base + lane + j * 64;
            const float mk = mP[idx], sk = sP[idx], pk = pP[idx];
            const float M  = fmaxf(m, mk);
            const float e1 = exp2_fast(m - M), e2 = exp2_fast(mk - M);
            s = s * e1 + sk * e2;
            p = p * e1 + pk * e2;
            m = M;
        }
    } else {
        if (lane < PPN) {
            m = mP[base + lane]; s = sP[base + lane]; p = pP[base + lane];
        }
    }

#pragma unroll
    for (int off = 1; off < 64; off <<= 1) {
        const float mo = __shfl_xor(m, off);
        const float so = __shfl_xor(s, off);
        const float po = __shfl_xor(p, off);
        const float M  = fmaxf(m, mo);
        const float e1 = exp2_fast(m - M), e2 = exp2_fast(mo - M);
        s = s * e1 + so * e2;
        p = p * e1 + po * e2;
        m = M;
    }

    if (lane == 0) out[wgid] = p / s;
}

extern "C" void kernel_launch(void* const* d_in, const int* in_sizes, int n_in,
                              void* d_out, int out_size, void* d_ws, size_t ws_size,
                              hipStream_t stream)
{
    (void)in_sizes; (void)n_in; (void)out_size;
    const float* data    = (const float*)d_in[0];
    const float* targets = (const float*)d_in[1];
    const float* W       = (const float*)d_in[2];
    float* out = (float*)d_out;

    const size_t plane4 = (size_t)BB * NN * (TT >> 4);   // GB=4: 128 partials/(b,n)
    const size_t plane6 = (size_t)BB * NN * (TT >> 6);   // GB=6: 32 partials/(b,n)
    const size_t seg32  = (size_t)BB * 32 * TT;
    const size_t seg16  = (size_t)BB * 16 * TT;

    if (ws_size >= (3 * plane4 + seg32) * sizeof(float)) {
        // ~58 MB path: SEG=32 (short serial chains, 8192 blocks), GB=4
        float* mP = (float*)d_ws;
        float* sP = mP + plane4;
        float* pP = sP + plane4;
        float* sg = pP + plane4;
        segsum_kernel<32><<<BB * CHUNKS * 32, 256, 0, stream>>>(data, targets, W, sg);
        scan_kernel<32, 4><<<BB * CHUNKS * 32, 256, 0, stream>>>(data, targets, W, sg, mP, sP, pP);
        combine_kernel<128><<<(BB * NN) / 4, 256, 0, stream>>>(mP, sP, pP, out);
    } else if (ws_size >= (3 * plane4 + seg16) * sizeof(float)) {
        // ~54 MB path: SEG=16, GB=4 (R7-equivalent + exp2)
        float* mP = (float*)d_ws;
        float* sP = mP + plane4;
        float* pP = sP + plane4;
        float* sg = pP + plane4;
        segsum_kernel<16><<<BB * CHUNKS * 16, 256, 0, stream>>>(data, targets, W, sg);
        scan_kernel<16, 4><<<BB * CHUNKS * 16, 256, 0, stream>>>(data, targets, W, sg, mP, sP, pP);
        combine_kernel<128><<<(BB * NN) / 4, 256, 0, stream>>>(mP, sP, pP, out);
    } else if (ws_size >= (3 * plane6 + seg16) * sizeof(float)) {
        // ~17 MB path: SEG=16, GB=6
        float* mP = (float*)d_ws;
        float* sP = mP + plane6;
        float* pP = sP + plane6;
        float* sg = pP + plane6;
        segsum_kernel<16><<<BB * CHUNKS * 16, 256, 0, stream>>>(data, targets, W, sg);
        scan_kernel<16, 6><<<BB * CHUNKS * 16, 256, 0, stream>>>(data, targets, W, sg, mP, sP, pP);
        combine_kernel<32><<<(BB * NN) / 4, 256, 0, stream>>>(mP, sP, pP, out);
    } else {
        // 12 MB fallback: no segmentation (slow but correct)
        float* mP = (float*)d_ws;
        float* sP = mP + plane6;
        float* pP = sP + plane6;
        scan_kernel<1, 6><<<BB * CHUNKS, 256, 0, stream>>>(data, targets, W, nullptr, mP, sP, pP);
        combine_kernel<32><<<(BB * NN) / 4, 256, 0, stream>>>(mP, sP, pP, out);
    }
}

// Round 12
// 301.891 us; speedup vs baseline: 1.4491x; 1.1263x over previous
//
#include <hip/hip_runtime.h>
#include <hip/hip_bf16.h>
#include <math.h>

// Problem constants (from reference setup_inputs)
#define BB 32
#define NN 1024
#define DD 64
#define TT 2048
#define CHUNKS (TT / 256)   // 8 column-chunks of 256
#define SEGS 16             // n-segments (decoupled scan)

typedef float f32x4 __attribute__((ext_vector_type(4)));

// alpha in LOG2 units: exp() becomes bare v_exp_f32. Validated R9/R10.
#define NLOG2E_HALF (-0.72134752044448169f)   // -0.5 * log2(e)

__device__ __forceinline__ float exp2_fast(float x) {
    return __builtin_amdgcn_exp2f(x);
}

// DPP move WITHOUT tied-old operand -> fuses into the consumer op.
template<int CTRL>
__device__ __forceinline__ float dpp_mov_f(float v) {
    return __int_as_float(
        __builtin_amdgcn_mov_dpp(__float_as_int(v), CTRL, 0xF, 0xF, true));
}

// All-lanes butterfly reduce over groups of 2^GB lanes.
template<int GB>
__device__ __forceinline__ float groupMax(float v) {
    v = fmaxf(v, dpp_mov_f<0x0B1>(v));  // xor1
    v = fmaxf(v, dpp_mov_f<0x04E>(v));  // xor2
    v = fmaxf(v, dpp_mov_f<0x141>(v));  // xor4 (row_half_mirror)
    v = fmaxf(v, dpp_mov_f<0x140>(v));  // xor8 (row_mirror)
    if constexpr (GB == 6) {
        v = fmaxf(v, __shfl_xor(v, 16));
        v = fmaxf(v, __shfl_xor(v, 32));
    }
    return v;
}

template<int GB>
__device__ __forceinline__ float groupSum(float v) {
    v += dpp_mov_f<0x0B1>(v);
    v += dpp_mov_f<0x04E>(v);
    v += dpp_mov_f<0x141>(v);
    v += dpp_mov_f<0x140>(v);
    if constexpr (GB == 6) {
        v += __shfl_xor(v, 16);
        v += __shfl_xor(v, 32);
    }
    return v;
}

__device__ __forceinline__ void loadW(const float* __restrict__ W, int col,
                                      f32x4* wv) {
#pragma unroll
    for (int i = 0; i < 16; ++i) {
        wv[i].x = W[(size_t)(4 * i + 0) * TT + col];
        wv[i].y = W[(size_t)(4 * i + 1) * TT + col];
        wv[i].z = W[(size_t)(4 * i + 2) * TT + col];
        wv[i].w = W[(size_t)(4 * i + 3) * TT + col];
    }
}

__device__ __forceinline__ float hsum(f32x4 s) {
    return (s.x + s.y) + (s.z + s.w);
}

// 4 independent dots vs the same W column (plain loop, compiler-scheduled;
// R9 lesson: manual pipelining of this regresses 2.2x).
__device__ __forceinline__ void dot4(const float* __restrict__ x0p,
                                     const f32x4* wv, float* xw) {
    const f32x4* xr0 = (const f32x4*)(x0p);
    const f32x4* xr1 = (const f32x4*)(x0p + DD);
    const f32x4* xr2 = (const f32x4*)(x0p + 2 * DD);
    const f32x4* xr3 = (const f32x4*)(x0p + 3 * DD);
    f32x4 s0 = {0.f, 0.f, 0.f, 0.f};
    f32x4 s1 = {0.f, 0.f, 0.f, 0.f};
    f32x4 s2 = {0.f, 0.f, 0.f, 0.f};
    f32x4 s3 = {0.f, 0.f, 0.f, 0.f};
#pragma unroll
    for (int i = 0; i < 16; ++i) {
        const f32x4 w = wv[i];
        s0 += xr0[i] * w;
        s1 += xr1[i] * w;
        s2 += xr2[i] * w;
        s3 += xr3[i] * w;
    }
    xw[0] = hsum(s0); xw[1] = hsum(s1); xw[2] = hsum(s2); xw[3] = hsum(s3);
}

// Pass A: per-(b, t, segment) sum of log-probs (log2 units). At its issue
// floor (~65 us, R5) — unchanged.
template<int SEG>
__global__ __launch_bounds__(256, 4)
void segsum_kernel(const float* __restrict__ data,
                   const float* __restrict__ targets,
                   const float* __restrict__ W,
                   float* __restrict__ segsum)
{
    constexpr int NSEG = NN / SEG;
    const int blk   = blockIdx.x;
    const int s     = blk % SEG;
    const int rem   = blk / SEG;
    const int chunk = rem % CHUNKS;
    const int b     = rem / CHUNKS;
    const int tid   = threadIdx.x;
    const int col   = chunk * 256 + tid;

    f32x4 wv[16];
    loadW(W, col, wv);

    const float* xb = data + (size_t)b * NN * DD;
    const float* tb = targets + (size_t)b * NN;

    const int n0 = s * NSEG;
    float acc = 0.0f;
    for (int n = n0; n < n0 + NSEG; n += 4) {
        float xw[4];
        dot4(xb + (size_t)n * DD, wv, xw);
#pragma unroll
        for (int j = 0; j < 4; ++j) {
            const float d = tb[n + j] - xw[j];
            acc = fmaf(d * d, NLOG2E_HALF, acc);
        }
    }
    segsum[((size_t)b * SEG + s) * TT + col] = acc;
}

// Pass B: dual-stream scan. One block handles TWO independent segments
// (sA, sB = sA + SEG/2) with shared W registers. The two alpha chains are
// independent, so stream B's FMAs/trees fill stream A's DPP/exp dependency
// stalls (and vice versa) — in-wave ILP with zero added instructions.
// Per-stream FP order identical to R7 -> bitwise-equal partials.
template<int SEG, int GB>
__global__ __launch_bounds__(256)
void scan2_kernel(const float* __restrict__ data,
                  const float* __restrict__ targets,
                  const float* __restrict__ W,
                  const float* __restrict__ segsum,
                  float* __restrict__ mP,
                  float* __restrict__ sP,
                  float* __restrict__ pP)
{
    constexpr int NSEG = NN / SEG;
    constexpr int HALF = SEG / 2;
    constexpr int PPN  = TT >> GB;            // partials per (b,n)
    const int blk   = blockIdx.x;
    const int sA    = blk % HALF;
    const int rem   = blk / HALF;
    const int chunk = rem % CHUNKS;
    const int b     = rem / CHUNKS;
    const int sB    = sA + HALF;
    const int tid   = threadIdx.x;
    const int lane  = tid & 63;
    const int col   = chunk * 256 + tid;

    f32x4 wv[16];
    loadW(W, col, wv);

    const float* xb = data + (size_t)b * NN * DD;
    const float* tb = targets + (size_t)b * NN;

    const int  k      = (chunk * 256 + (tid & ~((1 << GB) - 1))) >> GB;
    const bool writer = (lane & ((1 << GB) - 1)) == 0;
    const size_t base0 = (size_t)b * NN * PPN + k;

    // exclusive segment prefixes for both streams (log2 units)
    float alphaA = 0.0f, alphaB = 0.0f;
    for (int s2 = 0; s2 < sB; ++s2) {
        const float v = segsum[((size_t)b * SEG + s2) * TT + col];
        alphaB += v;
        if (s2 < sA) alphaA += v;
    }

    // full softmax+emit for one quad of one stream; updates that alpha.
    auto quad = [&](float& alpha, int n) {
        float xw[4];
        dot4(xb + (size_t)n * DD, wv, xw);
        float a[4];
        float al = alpha;
#pragma unroll
        for (int j = 0; j < 4; ++j) {
            a[j] = al;
            const float d = tb[n + j] - xw[j];
            al = fmaf(d * d, NLOG2E_HALF, al);
        }
        alpha = al;
        float m[4], e[4], qv[4], sv[4], pv[4];
#pragma unroll
        for (int j = 0; j < 4; ++j) m[j] = groupMax<GB>(a[j]);
#pragma unroll
        for (int j = 0; j < 4; ++j) {
            e[j]  = exp2_fast(a[j] - m[j]);
            qv[j] = e[j] * xw[j];
        }
#pragma unroll
        for (int j = 0; j < 4; ++j) sv[j] = groupSum<GB>(e[j]);
#pragma unroll
        for (int j = 0; j < 4; ++j) pv[j] = groupSum<GB>(qv[j]);
        if (writer) {
            const size_t i0 = base0 + (size_t)n * PPN;
#pragma unroll
            for (int j = 0; j < 4; ++j) {
                mP[i0 + (size_t)j * PPN] = m[j];
                sP[i0 + (size_t)j * PPN] = sv[j];
                pP[i0 + (size_t)j * PPN] = pv[j];
            }
        }
    };

    const int nA0 = sA * NSEG;
    const int nB0 = sB * NSEG;
#pragma unroll 1
    for (int i = 0; i < NSEG; i += 4) {
        quad(alphaA, nA0 + i);   // two independent streams: the compiler
        quad(alphaB, nB0 + i);   // interleaves them to fill dep stalls
    }
}

// Single-stream scan (fallback path only).
template<int SEG, int GB>
__global__ __launch_bounds__(256, 4)
void scan_kernel(const float* __restrict__ data,
                 const float* __restrict__ targets,
                 const float* __restrict__ W,
                 const float* __restrict__ segsum,
                 float* __restrict__ mP,
                 float* __restrict__ sP,
                 float* __restrict__ pP)
{
    constexpr int NSEG = NN / SEG;
    constexpr int PPN  = TT >> GB;
    const int blk   = blockIdx.x;
    const int s     = blk % SEG;
    const int rem   = blk / SEG;
    const int chunk = rem % CHUNKS;
    const int b     = rem / CHUNKS;
    const int tid   = threadIdx.x;
    const int lane  = tid & 63;
    const int col   = chunk * 256 + tid;

    f32x4 wv[16];
    loadW(W, col, wv);

    const float* xb = data + (size_t)b * NN * DD;
    const float* tb = targets + (size_t)b * NN;

    const int  k      = (chunk * 256 + (tid & ~((1 << GB) - 1))) >> GB;
    const bool writer = (lane & ((1 << GB) - 1)) == 0;
    const size_t base0 = (size_t)b * NN * PPN + k;

    float alpha = 0.0f;
    if constexpr (SEG > 1) {
        for (int s2 = 0; s2 < s; ++s2)
            alpha += segsum[((size_t)b * SEG + s2) * TT + col];
    }

    const int n0 = s * NSEG;
    for (int n = n0; n < n0 + NSEG; n += 4) {
        float xw[4];
        dot4(xb + (size_t)n * DD, wv, xw);
        float a[4];
        float al = alpha;
#pragma unroll
        for (int j = 0; j < 4; ++j) {
            a[j] = al;
            const float d = tb[n + j] - xw[j];
            al = fmaf(d * d, NLOG2E_HALF, al);
        }
        alpha = al;
        float m[4], e[4], qv[4], sv[4], pv[4];
#pragma unroll
        for (int j = 0; j < 4; ++j) m[j] = groupMax<GB>(a[j]);
#pragma unroll
        for (int j = 0; j < 4; ++j) {
            e[j]  = exp2_fast(a[j] - m[j]);
            qv[j] = e[j] * xw[j];
        }
#pragma unroll
        for (int j = 0; j < 4; ++j) sv[j] = groupSum<GB>(e[j]);
#pragma unroll
        for (int j = 0; j < 4; ++j) pv[j] = groupSum<GB>(qv[j]);
        if (writer) {
            const size_t i0 = base0 + (size_t)n * PPN;
#pragma unroll
            for (int j = 0; j < 4; ++j) {
                mP[i0 + (size_t)j * PPN] = m[j];
                sP[i0 + (size_t)j * PPN] = sv[j];
                pP[i0 + (size_t)j * PPN] = pv[j];
            }
        }
    }
}

// Pass C: one wave per (b,n): merge PPN partials (log2 units).
template<int PPN>
__global__ __launch_bounds__(256)
void combine_kernel(const float* __restrict__ mP,
                    const float* __restrict__ sP,
                    const float* __restrict__ pP,
                    float* __restrict__ out)
{
    const int wgid = blockIdx.x * 4 + (threadIdx.x >> 6);   // = b*NN + n
    const int lane = threadIdx.x & 63;
    const size_t base = (size_t)wgid * PPN;

    float m = -INFINITY, s = 0.0f, p = 0.0f;
    if constexpr (PPN >= 64) {
#pragma unroll
        for (int j = 0; j < PPN / 64; ++j) {
            const size_t idx = base + lane + j * 64;
            const float mk = mP[idx], sk = sP[idx], pk = pP[idx];
            const float M  = fmaxf(m, mk);
            const float e1 = exp2_fast(m - M), e2 = exp2_fast(mk - M);
            s = s * e1 + sk * e2;
            p = p * e1 + pk * e2;
            m = M;
        }
    } else {
        if (lane < PPN) {
            m = mP[base + lane]; s = sP[base + lane]; p = pP[base + lane];
        }
    }

#pragma unroll
    for (int off = 1; off < 64; off <<= 1) {
        const float mo = __shfl_xor(m, off);
        const float so = __shfl_xor(s, off);
        const float po = __shfl_xor(p, off);
        const float M  = fmaxf(m, mo);
        const float e1 = exp2_fast(m - M), e2 = exp2_fast(mo - M);
        s = s * e1 + so * e2;
        p = p * e1 + po * e2;
        m = M;
    }

    if (lane == 0) out[wgid] = p / s;
}

extern "C" void kernel_launch(void* const* d_in, const int* in_sizes, int n_in,
                              void* d_out, int out_size, void* d_ws, size_t ws_size,
                              hipStream_t stream)
{
    (void)in_sizes; (void)n_in; (void)out_size;
    const float* data    = (const float*)d_in[0];
    const float* targets = (const float*)d_in[1];
    const float* W       = (const float*)d_in[2];
    float* out = (float*)d_out;

    const size_t plane4 = (size_t)BB * NN * (TT >> 4);   // GB=4: 128 partials/(b,n)
    const size_t plane6 = (size_t)BB * NN * (TT >> 6);   // GB=6: 32 partials/(b,n)
    const size_t seg16  = (size_t)BB * SEGS * TT;

    if (ws_size >= (3 * plane4 + seg16) * sizeof(float)) {
        // ~54 MB path: SEG=16, GB=4, dual-stream scan
        float* mP = (float*)d_ws;
        float* sP = mP + plane4;
        float* pP = sP + plane4;
        float* sg = pP + plane4;
        segsum_kernel<SEGS><<<BB * CHUNKS * SEGS, 256, 0, stream>>>(data, targets, W, sg);
        scan2_kernel<SEGS, 4><<<BB * CHUNKS * (SEGS / 2), 256, 0, stream>>>(data, targets, W, sg, mP, sP, pP);
        combine_kernel<128><<<(BB * NN) / 4, 256, 0, stream>>>(mP, sP, pP, out);
    } else if (ws_size >= (3 * plane6 + seg16) * sizeof(float)) {
        // ~17 MB path: SEG=16, GB=6, dual-stream scan
        float* mP = (float*)d_ws;
        float* sP = mP + plane6;
        float* pP = sP + plane6;
        float* sg = pP + plane6;
        segsum_kernel<SEGS><<<BB * CHUNKS * SEGS, 256, 0, stream>>>(data, targets, W, sg);
        scan2_kernel<SEGS, 6><<<BB * CHUNKS * (SEGS / 2), 256, 0, stream>>>(data, targets, W, sg, mP, sP, pP);
        combine_kernel<32><<<(BB * NN) / 4, 256, 0, stream>>>(mP, sP, pP, out);
    } else {
        // 12 MB fallback: no segmentation (slow but correct)
        float* mP = (float*)d_ws;
        float* sP = mP + plane6;
        float* pP = sP + plane6;
        scan_kernel<1, 6><<<BB * CHUNKS, 256, 0, stream>>>(data, targets, W, nullptr, mP, sP, pP);
        combine_kernel<32><<<(BB * NN) / 4, 256, 0, stream>>>(mP, sP, pP, out);
    }
}